// Round 5
// baseline (124.264 us; speedup 1.0000x reference)
//
#include <hip/hip_runtime.h>
#include <math.h>

// Problem dims (hardcoded per reference setup_inputs)
#define N_  8
#define C_  256
#define T_  30
#define H_  64
#define W_  44
#define S_  8      // NUM_STRIPES
#define SH_ 8      // H_/S_

#define ROWS      (N_*C_*T_)      // 61440 rows of H*W = 2816 floats
#define NFEATS    (ROWS*S_)       // 491520
#define STRIPE_F4 (SH_*W_/4)      // 88 float4 per stripe

#define ROWS_PER_WAVE 8
#define WAVES_ST1 (ROWS / ROWS_PER_WAVE)   // 7680 waves -> all co-resident
#define BLOCKS_ST1 (WAVES_ST1 / 4)         // 1920 blocks of 256

// clang-native vector type: __builtin_nontemporal_load requires it
typedef float vf4 __attribute__((ext_vector_type(4)));

// ---------------- Stage 1: each wave -> 8 rows (2 adjacent rows x 4 iterations).
// Within a row: 8 lanes per stripe, lane (8j+r) reads float4 88j + r + 8i, i=0..10.
// Each load instruction = 8 aligned 128B segments = 16 full 64B lines, 0 waste.
// Nontemporal: x is read exactly once, don't pollute L1/L2.
// Output layout: feats2[((n*S+s)*T+t)*C+c]  -> stage 2/3 read contiguously.
__global__ __launch_bounds__(256) void feats_kernel(const float* __restrict__ x,
                                                    float* __restrict__ feats2) {
    const int wid  = (blockIdx.x * blockDim.x + threadIdx.x) >> 6;
    const int lane = threadIdx.x & 63;
    const int j = lane >> 3;        // stripe 0..7
    const int r = lane & 7;         // slot within stripe
    const int off = STRIPE_F4 * j + r;

    #pragma unroll 1
    for (int it = 0; it < 4; ++it) {
        const int row0 = 2 * wid + it * (2 * WAVES_ST1);

        const vf4* p0 = (const vf4*)(x + (size_t)row0 * (H_*W_)) + off;
        const vf4* p1 = p0 + (H_*W_/4);   // row0 + 1 (adjacent)

        vf4 a0 = (vf4)(0.f);
        vf4 a1 = (vf4)(0.f);
        #pragma unroll
        for (int i = 0; i < 11; ++i) {
            vf4 v0 = __builtin_nontemporal_load(p0 + 8 * i);
            vf4 v1 = __builtin_nontemporal_load(p1 + 8 * i);
            a0 += v0;
            a1 += v1;
        }
        float s0 = (a0.x + a0.y) + (a0.z + a0.w);
        float s1 = (a1.x + a1.y) + (a1.z + a1.w);
        s0 += __shfl_xor(s0, 1, 64);
        s0 += __shfl_xor(s0, 2, 64);
        s0 += __shfl_xor(s0, 4, 64);
        s1 += __shfl_xor(s1, 1, 64);
        s1 += __shfl_xor(s1, 2, 64);
        s1 += __shfl_xor(s1, 4, 64);
        if (r == 0) {
            // row = (n*C + c)*T + t
            const int n0 = row0 / (C_ * T_);
            const int rem0 = row0 % (C_ * T_);
            const int c0 = rem0 / T_, t0 = rem0 % T_;
            const int row1 = row0 + 1;
            const int n1 = row1 / (C_ * T_);
            const int rem1 = row1 % (C_ * T_);
            const int c1 = rem1 / T_, t1 = rem1 % T_;
            feats2[(((size_t)n0 * S_ + j) * T_ + t0) * C_ + c0] = s0 * (1.0f / (SH_ * W_));
            feats2[(((size_t)n1 * S_ + j) * T_ + t1) * C_ + c1] = s1 * (1.0f / (SH_ * W_));
        }
    }
}

// ---------------- Stage 2+3 fused: per (n,s) block: scores over t, top-2, output.
// feats2[n][s] is a contiguous [T][C] = 30x256 panel -> all reads coalesced.
__global__ __launch_bounds__(256) void out_kernel(const float* __restrict__ feats2,
                                                  float* __restrict__ out) {
    __shared__ float sc[32];
    const int b = blockIdx.x;          // 0..63 = n*S+s
    const int n = b >> 3, s = b & 7;
    const int tid = threadIdx.x, lane = tid & 63, w = tid >> 6;
    const float* f = feats2 + (size_t)b * (T_ * C_);   // [t][c]

    // scores[t] = sqrt(max(sum_c f[t][c]^2, eps)); waves split the t's
    for (int t = w; t < T_; t += 4) {
        vf4 v = ((const vf4*)(f + t * C_))[lane];      // 64 lanes x float4 = 256 c
        float sum = v.x * v.x + v.y * v.y + v.z * v.z + v.w * v.w;
        #pragma unroll
        for (int o = 32; o; o >>= 1) sum += __shfl_xor(sum, o, 64);
        if (lane == 0) sc[t] = sqrtf(fmaxf(sum, 1e-6f));
    }
    __syncthreads();

    // stable top-2 (first occurrence wins ties) — redundantly per thread, cheap
    int i0 = 0; float v0 = sc[0];
    for (int t = 1; t < T_; ++t) { float v = sc[t]; if (v > v0) { v0 = v; i0 = t; } }
    int i1 = (i0 == 0) ? 1 : 0; float v1 = sc[i1];
    for (int t = 0; t < T_; ++t) {
        if (t == i0) continue;
        float v = sc[t]; if (v > v1) { v1 = v; i1 = t; }
    }

    const int c = tid;                 // one thread per channel; contiguous reads
    out[n * (S_ * C_) + s * C_ + c] = 0.5f * (f[i0 * C_ + c] + f[i1 * C_ + c]);
}

extern "C" void kernel_launch(void* const* d_in, const int* in_sizes, int n_in,
                              void* d_out, int out_size, void* d_ws, size_t ws_size,
                              hipStream_t stream) {
    const float* x = (const float*)d_in[0];
    float* out = (float*)d_out;
    float* feats2 = (float*)d_ws;      // NFEATS floats (~1.97 MB), [n][s][t][c]

    feats_kernel<<<BLOCKS_ST1, 256, 0, stream>>>(x, feats2);
    out_kernel<<<N_ * S_, 256, 0, stream>>>(feats2, out);
}

// Round 6
// 121.966 us; speedup vs baseline: 1.0188x; 1.0188x over previous
//
#include <hip/hip_runtime.h>
#include <math.h>

// Problem dims (hardcoded per reference setup_inputs)
#define N_  8
#define C_  256
#define T_  30
#define H_  64
#define W_  44
#define S_  8      // NUM_STRIPES
#define SH_ 8      // H_/S_

#define ROWS      (N_*C_*T_)      // 61440 rows of H*W = 2816 floats
#define NFEATS    (ROWS*S_)       // 491520
#define STRIPE_F4 (SH_*W_/4)      // 88 float4 per stripe

#define ROWS_PER_WAVE 4
#define WAVES_ST1 (ROWS / ROWS_PER_WAVE)   // 15360 waves
#define BLOCKS_ST1 (WAVES_ST1 / 4)         // 3840 blocks of 256

// clang-native vector type: __builtin_nontemporal_load requires it
typedef float vf4 __attribute__((ext_vector_type(4)));

// ---------------- Stage 1: each wave -> 4 rows (2 adjacent rows x 2 iterations).
// Within a row: 8 lanes per stripe, lane (8j+r) reads float4 88j + r + 8i, i=0..10.
// Each load instruction = 8 aligned 128B segments = 16 full 64B lines, 0 waste.
// Nontemporal: x is read exactly once, don't pollute L1/L2.
// Output layout: feats2[((n*S+s)*T+t)*C+c]  -> stage 2/3 read contiguously.
__global__ __launch_bounds__(256) void feats_kernel(const float* __restrict__ x,
                                                    float* __restrict__ feats2) {
    const int wid  = (blockIdx.x * blockDim.x + threadIdx.x) >> 6;
    const int lane = threadIdx.x & 63;
    const int j = lane >> 3;        // stripe 0..7
    const int r = lane & 7;         // slot within stripe
    const int off = STRIPE_F4 * j + r;

    #pragma unroll 1
    for (int it = 0; it < 2; ++it) {
        const int row0 = 2 * wid + it * (2 * WAVES_ST1);

        const vf4* p0 = (const vf4*)(x + (size_t)row0 * (H_*W_)) + off;
        const vf4* p1 = p0 + (H_*W_/4);   // row0 + 1 (adjacent)

        vf4 a0 = (vf4)(0.f);
        vf4 a1 = (vf4)(0.f);
        #pragma unroll
        for (int i = 0; i < 11; ++i) {
            vf4 v0 = __builtin_nontemporal_load(p0 + 8 * i);
            vf4 v1 = __builtin_nontemporal_load(p1 + 8 * i);
            a0 += v0;
            a1 += v1;
        }
        float s0 = (a0.x + a0.y) + (a0.z + a0.w);
        float s1 = (a1.x + a1.y) + (a1.z + a1.w);
        s0 += __shfl_xor(s0, 1, 64);
        s0 += __shfl_xor(s0, 2, 64);
        s0 += __shfl_xor(s0, 4, 64);
        s1 += __shfl_xor(s1, 1, 64);
        s1 += __shfl_xor(s1, 2, 64);
        s1 += __shfl_xor(s1, 4, 64);
        if (r == 0) {
            // row = (n*C + c)*T + t ; consecutive rows share (n,c), t & t+1
            const int n0 = row0 / (C_ * T_);
            const int rem0 = row0 % (C_ * T_);
            const int c0 = rem0 / T_, t0 = rem0 % T_;
            const size_t base = ((size_t)n0 * S_ + j) * T_ * C_ + (size_t)t0 * C_ + c0;
            feats2[base]      = s0 * (1.0f / (SH_ * W_));   // (n0,j,t0,  c0)
            feats2[base + C_] = s1 * (1.0f / (SH_ * W_));   // (n0,j,t0+1,c0) — t0 is even
        }
    }
}

// ---------------- Stage 2+3 fused: per (n,s) block: scores over t, top-2, output.
// feats2[n][s] is a contiguous [T][C] = 30x256 panel -> all reads coalesced.
__global__ __launch_bounds__(256) void out_kernel(const float* __restrict__ feats2,
                                                  float* __restrict__ out) {
    __shared__ float sc[32];
    const int b = blockIdx.x;          // 0..63 = n*S+s
    const int n = b >> 3, s = b & 7;
    const int tid = threadIdx.x, lane = tid & 63, w = tid >> 6;
    const float* f = feats2 + (size_t)b * (T_ * C_);   // [t][c]

    // scores[t] = sqrt(max(sum_c f[t][c]^2, eps)); waves split the t's
    for (int t = w; t < T_; t += 4) {
        vf4 v = ((const vf4*)(f + t * C_))[lane];      // 64 lanes x float4 = 256 c
        float sum = v.x * v.x + v.y * v.y + v.z * v.z + v.w * v.w;
        #pragma unroll
        for (int o = 32; o; o >>= 1) sum += __shfl_xor(sum, o, 64);
        if (lane == 0) sc[t] = sqrtf(fmaxf(sum, 1e-6f));
    }
    __syncthreads();

    // stable top-2 (first occurrence wins ties) — redundantly per thread, cheap
    int i0 = 0; float v0 = sc[0];
    for (int t = 1; t < T_; ++t) { float v = sc[t]; if (v > v0) { v0 = v; i0 = t; } }
    int i1 = (i0 == 0) ? 1 : 0; float v1 = sc[i1];
    for (int t = 0; t < T_; ++t) {
        if (t == i0) continue;
        float v = sc[t]; if (v > v1) { v1 = v; i1 = t; }
    }

    const int c = tid;                 // one thread per channel; contiguous reads
    out[n * (S_ * C_) + s * C_ + c] = 0.5f * (f[i0 * C_ + c] + f[i1 * C_ + c]);
}

extern "C" void kernel_launch(void* const* d_in, const int* in_sizes, int n_in,
                              void* d_out, int out_size, void* d_ws, size_t ws_size,
                              hipStream_t stream) {
    const float* x = (const float*)d_in[0];
    float* out = (float*)d_out;
    float* feats2 = (float*)d_ws;      // NFEATS floats (~1.97 MB), [n][s][t][c]

    feats_kernel<<<BLOCKS_ST1, 256, 0, stream>>>(x, feats2);
    out_kernel<<<N_ * S_, 256, 0, stream>>>(feats2, out);
}

// Round 7
// 118.078 us; speedup vs baseline: 1.0524x; 1.0329x over previous
//
#include <hip/hip_runtime.h>
#include <math.h>

// Problem dims (hardcoded per reference setup_inputs)
#define N_  8
#define C_  256
#define T_  30
#define H_  64
#define W_  44
#define S_  8      // NUM_STRIPES
#define SH_ 8      // H_/S_

#define ROWS      (N_*C_*T_)      // 61440 rows of H*W = 2816 floats
#define NFEATS    (ROWS*S_)       // 491520
#define STRIPE_F4 (SH_*W_/4)      // 88 float4 per stripe

#define ROWS_PER_WAVE 4
#define WAVES_ST1 (ROWS / ROWS_PER_WAVE)   // 15360 waves
#define BLOCKS_ST1 (WAVES_ST1 / 4)         // 3840 blocks of 256

// clang-native vector type: __builtin_nontemporal_load requires it
typedef float vf4 __attribute__((ext_vector_type(4)));

// ---------------- Stage 1 (exact round-4 kernel, proven 118.8us config).
// Each wave -> 4 rows (2 adjacent rows x 2 iterations).
// Within a row: 8 lanes per stripe, lane (8j+r) reads float4 88j + r + 8i, i=0..10.
// Each load instruction = 8 aligned 128B segments = 16 full 64B lines, 0 waste.
// Layout A: feats[row*8 + stripe] -> the 8 lanes with r==0 store 32 contiguous bytes.
__global__ __launch_bounds__(256) void feats_kernel(const float* __restrict__ x,
                                                    float* __restrict__ feats) {
    const int wid  = (blockIdx.x * blockDim.x + threadIdx.x) >> 6;
    const int lane = threadIdx.x & 63;
    const int j = lane >> 3;        // stripe 0..7
    const int r = lane & 7;         // slot within stripe
    const int off = STRIPE_F4 * j + r;

    #pragma unroll 1
    for (int it = 0; it < 2; ++it) {
        const int row0 = 2 * wid + it * (2 * WAVES_ST1);

        const vf4* p0 = (const vf4*)(x + (size_t)row0 * (H_*W_)) + off;
        const vf4* p1 = p0 + (H_*W_/4);   // row0 + 1 (adjacent)

        vf4 a0 = (vf4)(0.f);
        vf4 a1 = (vf4)(0.f);
        #pragma unroll
        for (int i = 0; i < 11; ++i) {
            vf4 v0 = __builtin_nontemporal_load(p0 + 8 * i);
            vf4 v1 = __builtin_nontemporal_load(p1 + 8 * i);
            a0 += v0;
            a1 += v1;
        }
        float s0 = (a0.x + a0.y) + (a0.z + a0.w);
        float s1 = (a1.x + a1.y) + (a1.z + a1.w);
        s0 += __shfl_xor(s0, 1, 64);
        s0 += __shfl_xor(s0, 2, 64);
        s0 += __shfl_xor(s0, 4, 64);
        s1 += __shfl_xor(s1, 1, 64);
        s1 += __shfl_xor(s1, 2, 64);
        s1 += __shfl_xor(s1, 4, 64);
        if (r == 0) {
            feats[(size_t)row0 * S_ + j]       = s0 * (1.0f / (SH_ * W_));
            feats[(size_t)(row0 + 1) * S_ + j] = s1 * (1.0f / (SH_ * W_));
        }
    }
}

// ---------------- Stage 2+3 fused: per (n,s) block: scores over t, top-2, output.
// Change vs round 4: all 32 score loads issued up-front (independent), so the
// 8 reduce rounds pay ONE memory round-trip instead of 8 serial ones.
__global__ __launch_bounds__(256) void out_kernel(const float* __restrict__ feats,
                                                  float* __restrict__ out) {
    __shared__ float sc[32];
    const int b = blockIdx.x;          // 0..63 = n*S+s
    const int n = b >> 3, s = b & 7;
    const int tid = threadIdx.x, lane = tid & 63, w = tid >> 6;

    // batched loads: v[i][jj] = feats[n, c=lane+64jj, t=w+4i, s]
    float v[8][4];
    #pragma unroll
    for (int i = 0; i < 8; ++i) {
        const int t = w + 4 * i;
        #pragma unroll
        for (int jj = 0; jj < 4; ++jj) {
            const int c = lane + 64 * jj;
            v[i][jj] = (t < T_) ? feats[((size_t)(n * C_ + c) * T_ + t) * S_ + s] : 0.f;
        }
    }
    #pragma unroll
    for (int i = 0; i < 8; ++i) {
        const int t = w + 4 * i;
        float sum = v[i][0]*v[i][0] + v[i][1]*v[i][1] + v[i][2]*v[i][2] + v[i][3]*v[i][3];
        #pragma unroll
        for (int o = 32; o; o >>= 1) sum += __shfl_xor(sum, o, 64);
        if (lane == 0 && t < T_) sc[t] = sqrtf(fmaxf(sum, 1e-6f));
    }
    __syncthreads();

    // stable top-2 (first occurrence wins ties) — redundantly per thread, cheap
    int i0 = 0; float v0 = sc[0];
    for (int t = 1; t < T_; ++t) { float vv = sc[t]; if (vv > v0) { v0 = vv; i0 = t; } }
    int i1 = (i0 == 0) ? 1 : 0; float v1 = sc[i1];
    for (int t = 0; t < T_; ++t) {
        if (t == i0) continue;
        float vv = sc[t]; if (vv > v1) { v1 = vv; i1 = t; }
    }

    const int c = tid;                 // one thread per channel
    const size_t base = (size_t)(n * C_ + c) * T_;
    const float a  = feats[(base + i0) * S_ + s];
    const float bb = feats[(base + i1) * S_ + s];
    out[n * (S_ * C_) + s * C_ + c] = 0.5f * (a + bb);
}

extern "C" void kernel_launch(void* const* d_in, const int* in_sizes, int n_in,
                              void* d_out, int out_size, void* d_ws, size_t ws_size,
                              hipStream_t stream) {
    const float* x = (const float*)d_in[0];
    float* out = (float*)d_out;
    float* feats = (float*)d_ws;       // NFEATS floats (~1.97 MB), layout A

    feats_kernel<<<BLOCKS_ST1, 256, 0, stream>>>(x, feats);
    out_kernel<<<N_ * S_, 256, 0, stream>>>(feats, out);
}